// Round 12
// baseline (220.953 us; speedup 1.0000x reference)
//
#include <hip/hip_runtime.h>

#define HW    16384
#define CHW   1048576
#define EPSV  1e-5f
#define PITCH 68          // rows with K=64 contraction (+4 pad)
#define APITCH 132        // attention rows, K=128 contraction (+4 pad)

typedef short bf16x8 __attribute__((ext_vector_type(8)));
typedef float f32x4 __attribute__((ext_vector_type(4)));
typedef unsigned short u16x4 __attribute__((ext_vector_type(4)));
typedef unsigned short u16x8 __attribute__((ext_vector_type(8)));

static __device__ __forceinline__ unsigned short f2b(float f) {
    union { float f; unsigned int i; } x; x.f = f;
    unsigned int i = x.i + 0x7fffu + ((x.i >> 16) & 1u);   // RNE
    return (unsigned short)(i >> 16);
}

// 8 consecutive bf16 (8B-aligned LDS) as an MFMA operand fragment
static __device__ __forceinline__ bf16x8 frag_load(const unsigned short* p) {
    union { u16x4 h[2]; bf16x8 v; } u;
    u.h[0] = *(const u16x4*)(p);
    u.h[1] = *(const u16x4*)(p + 4);
    return u.v;
}
static __device__ __forceinline__ bf16x8 gfrag(const unsigned short* p) {
    return *(const bf16x8*)p;   // 16B-aligned global load (dwordx4)
}
// D[a_idx = g4+r][b_idx = i16]; both frags loaded with per-lane row = tile+i16
static __device__ __forceinline__ f32x4 mfma16(bf16x8 a, bf16x8 b, f32x4 c) {
    return __builtin_amdgcn_mfma_f32_16x16x32_bf16(a, b, c, 0, 0, 0);
}

// ---------------------------------------------------------------------------
// Kernel 0: weight prep (bf16 conversion + BN folding)
// ---------------------------------------------------------------------------
__global__ void prep_kernel(const float* __restrict__ Wq, const float* __restrict__ Wk,
                            const float* __restrict__ Wv,
                            const float* __restrict__ c1w,
                            const float* __restrict__ bn1s, const float* __restrict__ bn1b,
                            const float* __restrict__ bn1m, const float* __restrict__ bn1v,
                            const float* __restrict__ c2w,
                            const float* __restrict__ bn2s, const float* __restrict__ bn2b,
                            const float* __restrict__ bn2m, const float* __restrict__ bn2v,
                            unsigned short* __restrict__ Wqb, unsigned short* __restrict__ Wkb,
                            unsigned short* __restrict__ Wvb, unsigned short* __restrict__ W3b,
                            unsigned short* __restrict__ W2b, float* __restrict__ beta1,
                            float* __restrict__ beta2)
{
    int i = blockIdx.x * blockDim.x + threadIdx.x;
    if (i < 12288) {                                  // QKV weights: elementwise bf16
        int mat = i >> 12, r = i & 4095;
        const float* src = (mat == 0) ? Wq : ((mat == 1) ? Wk : Wv);
        unsigned short* dst = (mat == 0) ? Wqb : ((mat == 1) ? Wkb : Wvb);
        dst[r] = f2b(src[r]);
    } else if (i < 49152) {                           // conv1 3x3 folded
        int j = i - 12288;
        int dydx = j >> 12, r = j & 4095, o = r >> 6, c = r & 63;
        float inv = bn1s[o] * rsqrtf(bn1v[o] + EPSV);
        W3b[j] = f2b(c1w[o * 576 + c * 9 + dydx] * inv);
    } else if (i < 53248) {                           // conv2 1x1 folded
        int r = i - 49152, o = r >> 6;
        float inv = bn2s[o] * rsqrtf(bn2v[o] + EPSV);
        W2b[r] = f2b(c2w[r] * inv);
    } else if (i < 53376) {
        int j = i - 53248;
        if (j < 64) {
            float inv = bn1s[j] * rsqrtf(bn1v[j] + EPSV);
            beta1[j] = bn1b[j] - bn1m[j] * inv;
        } else {
            int o = j - 64;
            float inv = bn2s[o] * rsqrtf(bn2v[o] + EPSV);
            beta2[o] = bn2b[o] - bn2m[o] * inv;
        }
    }
}

// ---------------------------------------------------------------------------
// Kernel 1a: Q projection. One input tile in LDS (17.4 KB); natural VGPR
// (~64) + 8 blocks/CU (thread cap) -> up to 32 waves/CU.
// ---------------------------------------------------------------------------
__global__ __launch_bounds__(256, 4) void proj_q_kernel(
    const float* __restrict__ x1, const unsigned short* __restrict__ Wqb,
    const float* __restrict__ bq, unsigned short* __restrict__ qo)
{
    __shared__ __align__(16) unsigned short XT[128][PITCH];   // 17408 B
    int t = threadIdx.x;
    int b = blockIdx.x >> 7;
    int p0 = (blockIdx.x & 127) << 7;

    const float* xs = x1 + b * CHW + p0;
    for (int idx = t; idx < 1024; idx += 256) {   // 32 c-pairs x 32 p-quads
        int c0 = ((idx >> 5) & 31) << 1, p4 = (idx & 31) << 2;
        float4 a0 = *(const float4*)&xs[c0 * HW + p4];
        float4 a1 = *(const float4*)&xs[(c0 + 1) * HW + p4];
        *(unsigned int*)&XT[p4 + 0][c0] = f2b(a0.x) | ((unsigned int)f2b(a1.x) << 16);
        *(unsigned int*)&XT[p4 + 1][c0] = f2b(a0.y) | ((unsigned int)f2b(a1.y) << 16);
        *(unsigned int*)&XT[p4 + 2][c0] = f2b(a0.z) | ((unsigned int)f2b(a1.z) << 16);
        *(unsigned int*)&XT[p4 + 3][c0] = f2b(a0.w) | ((unsigned int)f2b(a1.w) << 16);
    }
    __syncthreads();

    int lane = t & 63, wid = t >> 6;
    int i16 = lane & 15;
    int g8 = (lane >> 4) << 3;
    int g4 = (lane >> 4) << 2;
    int pb = wid << 5;                 // wave's 32 positions (2 m-tiles)

    bf16x8 afr[2][2];                  // [mi][ks]
    #pragma unroll
    for (int mi = 0; mi < 2; ++mi)
        #pragma unroll
        for (int ks = 0; ks < 2; ++ks)
            afr[mi][ks] = frag_load(&XT[pb + mi * 16 + i16][ks * 32 + g8]);

    f32x4 zz = {0.f, 0.f, 0.f, 0.f};
    f32x4 acc[2][4];
    #pragma unroll
    for (int mi = 0; mi < 2; ++mi)
        #pragma unroll
        for (int nt = 0; nt < 4; ++nt) acc[mi][nt] = zz;

    #pragma unroll
    for (int ks = 0; ks < 2; ++ks)
        #pragma unroll
        for (int nt = 0; nt < 4; ++nt) {
            bf16x8 bw = gfrag(Wqb + (nt * 16 + i16) * 64 + ks * 32 + g8);
            acc[0][nt] = mfma16(afr[0][ks], bw, acc[0][nt]);
            acc[1][nt] = mfma16(afr[1][ks], bw, acc[1][nt]);
        }

    unsigned short* dst = qo + b * CHW + p0;
    #pragma unroll
    for (int nt = 0; nt < 4; ++nt) {
        int o = nt * 16 + i16;
        float bb = bq[o];
        #pragma unroll
        for (int mi = 0; mi < 2; ++mi) {
            u16x4 pk;
            pk[0] = f2b(acc[mi][nt][0] + bb);
            pk[1] = f2b(acc[mi][nt][1] + bb);
            pk[2] = f2b(acc[mi][nt][2] + bb);
            pk[3] = f2b(acc[mi][nt][3] + bb);
            *(u16x4*)&dst[o * HW + pb + mi * 16 + g4] = pk;
        }
    }
}

// ---------------------------------------------------------------------------
// Kernel 1b: K,V projections (sequential mats, shared xc tile). Same
// occupancy story as proj_q.
// ---------------------------------------------------------------------------
__global__ __launch_bounds__(256, 4) void proj_kv_kernel(
    const float* __restrict__ xc,
    const unsigned short* __restrict__ Wkb, const unsigned short* __restrict__ Wvb,
    const float* __restrict__ bk, const float* __restrict__ bv,
    unsigned short* __restrict__ ko, unsigned short* __restrict__ vo)
{
    __shared__ __align__(16) unsigned short XT[128][PITCH];   // 17408 B
    int t = threadIdx.x;
    int b = blockIdx.x >> 7;
    int p0 = (blockIdx.x & 127) << 7;

    const float* xs = xc + b * CHW + p0;
    for (int idx = t; idx < 1024; idx += 256) {
        int c0 = ((idx >> 5) & 31) << 1, p4 = (idx & 31) << 2;
        float4 a0 = *(const float4*)&xs[c0 * HW + p4];
        float4 a1 = *(const float4*)&xs[(c0 + 1) * HW + p4];
        *(unsigned int*)&XT[p4 + 0][c0] = f2b(a0.x) | ((unsigned int)f2b(a1.x) << 16);
        *(unsigned int*)&XT[p4 + 1][c0] = f2b(a0.y) | ((unsigned int)f2b(a1.y) << 16);
        *(unsigned int*)&XT[p4 + 2][c0] = f2b(a0.z) | ((unsigned int)f2b(a1.z) << 16);
        *(unsigned int*)&XT[p4 + 3][c0] = f2b(a0.w) | ((unsigned int)f2b(a1.w) << 16);
    }
    __syncthreads();

    int lane = t & 63, wid = t >> 6;
    int i16 = lane & 15;
    int g8 = (lane >> 4) << 3;
    int g4 = (lane >> 4) << 2;
    int pb = wid << 5;

    bf16x8 afr[2][2];
    #pragma unroll
    for (int mi = 0; mi < 2; ++mi)
        #pragma unroll
        for (int ks = 0; ks < 2; ++ks)
            afr[mi][ks] = frag_load(&XT[pb + mi * 16 + i16][ks * 32 + g8]);

    f32x4 zz = {0.f, 0.f, 0.f, 0.f};
    #pragma unroll
    for (int mat = 0; mat < 2; ++mat) {
        const unsigned short* Wmat = (mat == 0) ? Wkb : Wvb;
        unsigned short* dst = ((mat == 0) ? ko : vo) + b * CHW + p0;
        const float* bias = (mat == 0) ? bk : bv;

        f32x4 acc[2][4];
        #pragma unroll
        for (int mi = 0; mi < 2; ++mi)
            #pragma unroll
            for (int nt = 0; nt < 4; ++nt) acc[mi][nt] = zz;

        #pragma unroll
        for (int ks = 0; ks < 2; ++ks)
            #pragma unroll
            for (int nt = 0; nt < 4; ++nt) {
                bf16x8 bw = gfrag(Wmat + (nt * 16 + i16) * 64 + ks * 32 + g8);
                acc[0][nt] = mfma16(afr[0][ks], bw, acc[0][nt]);
                acc[1][nt] = mfma16(afr[1][ks], bw, acc[1][nt]);
            }

        #pragma unroll
        for (int nt = 0; nt < 4; ++nt) {
            int o = nt * 16 + i16;
            float bb = bias[o];
            #pragma unroll
            for (int mi = 0; mi < 2; ++mi) {
                u16x4 pk;
                pk[0] = f2b(acc[mi][nt][0] + bb);
                pk[1] = f2b(acc[mi][nt][1] + bb);
                pk[2] = f2b(acc[mi][nt][2] + bb);
                pk[3] = f2b(acc[mi][nt][3] + bb);
                *(u16x4*)&dst[o * HW + pb + mi * 16 + g4] = pk;
            }
        }
    }
}

// ---------------------------------------------------------------------------
// Kernel 2: attention per (b,c), 512 threads / 8 waves, wave owns 16 v-rows.
// QK^T: A=KT, B=QT (softmax reduction stays in-wave). PV swapped: A=PL (v),
// B=V direct-from-global (h) -> y stores packed u16x4, xc reads float4.
// Dynamic LDS: QT,KT [128][132] bf16 = 67584 B. VGPR ~128 -> 16 waves/CU cap.
// ---------------------------------------------------------------------------
__global__ __launch_bounds__(512) void attn_kernel(
    const unsigned short* __restrict__ q, const unsigned short* __restrict__ k,
    const unsigned short* __restrict__ v, const float* __restrict__ xc,
    const float* __restrict__ gamma_p, unsigned short* __restrict__ y)
{
    extern __shared__ __align__(16) unsigned short sarena[];
    unsigned short (*QT)[APITCH] = (unsigned short(*)[APITCH])sarena;
    unsigned short (*KT)[APITCH] = (unsigned short(*)[APITCH])(sarena + 16896);
    unsigned short (*PL)[APITCH] = QT;      // aliases QT after phase 1

    int t = threadIdx.x;
    int base = blockIdx.x * HW;

    for (int idx = t; idx < 1024; idx += 512) {    // 64 h-pairs x 16 w-octets
        int h0 = (idx >> 4) << 1, w8 = (idx & 15) << 3;
        u16x8 q0 = *(const u16x8*)&q[base + h0 * 128 + w8];
        u16x8 q1 = *(const u16x8*)&q[base + (h0 + 1) * 128 + w8];
        #pragma unroll
        for (int j = 0; j < 8; ++j)
            *(unsigned int*)&QT[w8 + j][h0] = (unsigned int)q0[j] | ((unsigned int)q1[j] << 16);
        u16x8 k0 = *(const u16x8*)&k[base + h0 * 128 + w8];
        u16x8 k1 = *(const u16x8*)&k[base + (h0 + 1) * 128 + w8];
        #pragma unroll
        for (int j = 0; j < 8; ++j)
            *(unsigned int*)&KT[w8 + j][h0] = (unsigned int)k0[j] | ((unsigned int)k1[j] << 16);
    }
    __syncthreads();

    int lane = t & 63, wid = t >> 6;
    int i16 = lane & 15;
    int g8 = (lane >> 4) << 3;
    int g4 = (lane >> 4) << 2;
    int m0 = wid << 4;               // 16 v-rows per wave

    f32x4 zz = {0.f, 0.f, 0.f, 0.f};
    f32x4 e[8];
    #pragma unroll
    for (int nt = 0; nt < 8; ++nt) e[nt] = zz;

    #pragma unroll
    for (int ks = 0; ks < 4; ++ks) {
        bf16x8 a0 = frag_load(&KT[m0 + i16][ks * 32 + g8]);
        #pragma unroll
        for (int nt = 0; nt < 8; ++nt) {
            bf16x8 bfq = frag_load(&QT[nt * 16 + i16][ks * 32 + g8]);
            e[nt] = mfma16(a0, bfq, e[nt]);
        }
    }
    __syncthreads();   // QT/KT reads complete; QT region becomes PL

    // softmax over w: reduce across nt (regs) and the 16-lane col group
    #pragma unroll
    for (int r = 0; r < 4; ++r) {
        float mx = e[0][r];
        #pragma unroll
        for (int nt = 1; nt < 8; ++nt) mx = fmaxf(mx, e[nt][r]);
        mx = fmaxf(mx, __shfl_xor(mx, 1));
        mx = fmaxf(mx, __shfl_xor(mx, 2));
        mx = fmaxf(mx, __shfl_xor(mx, 4));
        mx = fmaxf(mx, __shfl_xor(mx, 8));
        float pv[8];
        float s = 0.f;
        #pragma unroll
        for (int nt = 0; nt < 8; ++nt) {
            pv[nt] = __expf(e[nt][r] - mx);
            s += pv[nt];
        }
        s += __shfl_xor(s, 1);
        s += __shfl_xor(s, 2);
        s += __shfl_xor(s, 4);
        s += __shfl_xor(s, 8);
        float rinv = 1.f / s;
        int vr = m0 + g4 + r;
        #pragma unroll
        for (int nt = 0; nt < 8; ++nt)
            PL[vr][nt * 16 + i16] = f2b(pv[nt] * rinv);
    }
    // no barrier: PV's A-frags read only this wave's own 16 PL rows

    f32x4 o_[8];
    #pragma unroll
    for (int nt = 0; nt < 8; ++nt) o_[nt] = zz;

    bf16x8 ap[4];
    #pragma unroll
    for (int ks = 0; ks < 4; ++ks)
        ap[ks] = frag_load(&PL[m0 + i16][ks * 32 + g8]);

    const unsigned short* vb_ = v + base;
    #pragma unroll
    for (int ks = 0; ks < 4; ++ks)
        #pragma unroll
        for (int nt = 0; nt < 8; ++nt) {
            bf16x8 bv8 = gfrag(vb_ + (nt * 16 + i16) * 128 + ks * 32 + g8);
            o_[nt] = mfma16(ap[ks], bv8, o_[nt]);
        }

    float g = gamma_p[0];
    const float* xcb = xc + base;
    #pragma unroll
    for (int nt = 0; nt < 8; ++nt) {
        int hh = nt * 16 + i16;
        int v4 = m0 + g4;
        float4 xcv = *(const float4*)&xcb[hh * 128 + v4];
        u16x4 pk;
        pk[0] = f2b(fmaf(g, o_[nt][0], xcv.x));
        pk[1] = f2b(fmaf(g, o_[nt][1], xcv.y));
        pk[2] = f2b(fmaf(g, o_[nt][2], xcv.z));
        pk[3] = f2b(fmaf(g, o_[nt][3], xcv.w));
        *(u16x4*)&y[base + hh * 128 + v4] = pk;
    }
}

// ---------------------------------------------------------------------------
// Kernel 3: 3x3 conv + BN + ReLU + 1x1 conv + BN + ReLU, fused, MFMA.
// conv1: A=W3 (o), B=XT (p) -> packed Y2 u16x4 writes.
// conv2 swapped: A=Y2 (p), B=W2 (o2) -> packed float4 output stores.
// Dynamic LDS 70720 B: XT [4][130][68] (Y2 [256][68] aliases) -> 2 blocks/CU.
// ---------------------------------------------------------------------------
__global__ __launch_bounds__(512) void conv3_fused_kernel(
    const unsigned short* __restrict__ yin, const unsigned short* __restrict__ W3b,
    const unsigned short* __restrict__ W2b, const float* __restrict__ beta1,
    const float* __restrict__ beta2, float* __restrict__ out)
{
    extern __shared__ __align__(16) unsigned short arena[];
    unsigned short* XT = arena;              // 4*130*68 = 35360 shorts
    unsigned short* Y2 = arena;              // [256][68] alias (XT dead by then)

    int t = threadIdx.x;
    int b = blockIdx.x >> 6;
    int h0 = (blockIdx.x & 63) << 1;

    u16x4 z4 = {0, 0, 0, 0};
    if (t < 136) {                                    // zero w-halo rows 0,129
        int dy = t / 34, rr = t % 34;
        int row = (rr < 17) ? 0 : 129;
        int q4 = (rr % 17) << 2;
        *(u16x4*)&XT[(dy * 130 + row) * PITCH + q4] = z4;
    }
    const unsigned short* yb = yin + b * CHW;
    for (int idx = t; idx < 2048; idx += 512) {  // 4 dy x 32 c-pairs x 16 w-octets
        int dy = idx >> 9, c0 = ((idx >> 4) & 31) << 1, w8 = (idx & 15) << 3;
        int hh = h0 + dy - 1;
        u16x8 a0 = {0,0,0,0,0,0,0,0}, a1 = {0,0,0,0,0,0,0,0};
        if (hh >= 0 && hh < 128) {
            a0 = *(const u16x8*)&yb[c0 * HW + hh * 128 + w8];
            a1 = *(const u16x8*)&yb[(c0 + 1) * HW + hh * 128 + w8];
        }
        #pragma unroll
        for (int j = 0; j < 8; ++j)
            *(unsigned int*)&XT[(dy * 130 + w8 + 1 + j) * PITCH + c0] =
                (unsigned int)a0[j] | ((unsigned int)a1[j] << 16);
    }
    __syncthreads();

    int lane = t & 63, wid = t >> 6;
    int i16 = lane & 15;
    int g8 = (lane >> 4) << 3;
    int g4 = (lane >> 4) << 2;
    int orow  = wid >> 2;              // output row within pair
    int wbase = ((wid >> 1) & 1) << 6; // 64-wide half of the row
    int mbase = (wid & 1) << 1;        // 2 of the 4 o-tiles

    f32x4 zz = {0.f, 0.f, 0.f, 0.f};
    f32x4 acc[2][4];
    #pragma unroll
    for (int m = 0; m < 2; ++m)
        #pragma unroll
        for (int nt = 0; nt < 4; ++nt) acc[m][nt] = zz;

    #pragma unroll
    for (int dy = 0; dy < 3; ++dy)
        #pragma unroll
        for (int dx = 0; dx < 3; ++dx) {
            const unsigned short* wpl = W3b + (dy * 3 + dx) * 4096;
            const unsigned short* xpl = XT + ((dy + orow) * 130 + dx) * PITCH;
            #pragma unroll
            for (int ks = 0; ks < 2; ++ks) {
                bf16x8 bf0 = frag_load(xpl + (wbase + i16) * PITCH + ks * 32 + g8);
                bf16x8 bf1 = frag_load(xpl + (wbase + 16 + i16) * PITCH + ks * 32 + g8);
                bf16x8 bf2 = frag_load(xpl + (wbase + 32 + i16) * PITCH + ks * 32 + g8);
                bf16x8 bf3 = frag_load(xpl + (wbase + 48 + i16) * PITCH + ks * 32 + g8);
                #pragma unroll
                for (int m = 0; m < 2; ++m) {
                    bf16x8 a = gfrag(wpl + ((mbase + m) * 16 + i16) * 64 + ks * 32 + g8);
                    acc[m][0] = mfma16(a, bf0, acc[m][0]);
                    acc[m][1] = mfma16(a, bf1, acc[m][1]);
                    acc[m][2] = mfma16(a, bf2, acc[m][2]);
                    acc[m][3] = mfma16(a, bf3, acc[m][3]);
                }
            }
        }
    __syncthreads();   // all XT reads done before aliasing as Y2

    #pragma unroll
    for (int m = 0; m < 2; ++m) {
        int ob0 = (mbase + m) * 16 + g4;
        float b0 = beta1[ob0 + 0];
        float b1 = beta1[ob0 + 1];
        float b2 = beta1[ob0 + 2];
        float b3 = beta1[ob0 + 3];
        #pragma unroll
        for (int nt = 0; nt < 4; ++nt) {
            int p = orow * 128 + wbase + nt * 16 + i16;
            u16x4 pk;
            pk[0] = f2b(fmaxf(acc[m][nt][0] + b0, 0.f));
            pk[1] = f2b(fmaxf(acc[m][nt][1] + b1, 0.f));
            pk[2] = f2b(fmaxf(acc[m][nt][2] + b2, 0.f));
            pk[3] = f2b(fmaxf(acc[m][nt][3] + b3, 0.f));
            *(u16x4*)&Y2[p * PITCH + ob0] = pk;
        }
    }
    __syncthreads();

    // conv2 swapped: A = Y2 (p rows), B = W2 (o2 rows)
    int m0c = wid << 5;                // wave's 32 positions
    f32x4 acc2[2][4];
    #pragma unroll
    for (int m = 0; m < 2; ++m)
        #pragma unroll
        for (int nt = 0; nt < 4; ++nt) acc2[m][nt] = zz;

    #pragma unroll
    for (int ks = 0; ks < 2; ++ks) {
        bf16x8 ay0 = frag_load(Y2 + (m0c + i16) * PITCH + ks * 32 + g8);
        bf16x8 ay1 = frag_load(Y2 + (m0c + 16 + i16) * PITCH + ks * 32 + g8);
        #pragma unroll
        for (int nt = 0; nt < 4; ++nt) {
            bf16x8 bw = gfrag(W2b + (nt * 16 + i16) * 64 + ks * 32 + g8);
            acc2[0][nt] = mfma16(ay0, bw, acc2[0][nt]);
            acc2[1][nt] = mfma16(ay1, bw, acc2[1][nt]);
        }
    }

    float* ob = out + b * CHW;
    #pragma unroll
    for (int mi = 0; mi < 2; ++mi)
        #pragma unroll
        for (int nt = 0; nt < 4; ++nt) {
            int o2 = nt * 16 + i16;
            float bt = beta2[o2];
            int p = m0c + mi * 16 + g4;
            int orw = p >> 7, wl = p & 127;
            float4 vv;
            vv.x = fmaxf(acc2[mi][nt][0] + bt, 0.f);
            vv.y = fmaxf(acc2[mi][nt][1] + bt, 0.f);
            vv.z = fmaxf(acc2[mi][nt][2] + bt, 0.f);
            vv.w = fmaxf(acc2[mi][nt][3] + bt, 0.f);
            *(float4*)&ob[o2 * HW + (h0 + orw) * 128 + wl] = vv;
        }
}

// ---------------------------------------------------------------------------
extern "C" void kernel_launch(void* const* d_in, const int* in_sizes, int n_in,
                              void* d_out, int out_size, void* d_ws, size_t ws_size,
                              hipStream_t stream)
{
    const float* x1   = (const float*)d_in[0];
    const float* xc   = (const float*)d_in[1];
    const float* Wq   = (const float*)d_in[2];
    const float* bq   = (const float*)d_in[3];
    const float* Wk   = (const float*)d_in[4];
    const float* bk   = (const float*)d_in[5];
    const float* Wv   = (const float*)d_in[6];
    const float* bv   = (const float*)d_in[7];
    const float* gam  = (const float*)d_in[8];
    const float* c1w  = (const float*)d_in[9];
    const float* bn1s = (const float*)d_in[10];
    const float* bn1b = (const float*)d_in[11];
    const float* bn1m = (const float*)d_in[12];
    const float* bn1v = (const float*)d_in[13];
    const float* c2w  = (const float*)d_in[14];
    const float* bn2s = (const float*)d_in[15];
    const float* bn2b = (const float*)d_in[16];
    const float* bn2m = (const float*)d_in[17];
    const float* bn2v = (const float*)d_in[18];
    float* out = (float*)d_out;

    char* ws = (char*)d_ws;
    const size_t BUF = 16777216;   // one bf16 [B,C,H,W] buffer
    unsigned short* qb  = (unsigned short*)(ws);
    unsigned short* kb  = (unsigned short*)(ws + BUF);
    unsigned short* vb  = (unsigned short*)(ws + 2 * BUF);
    unsigned short* yb  = (unsigned short*)(ws + 3 * BUF);
    unsigned short* Wqb = (unsigned short*)(ws + 4 * BUF);
    unsigned short* Wkb = Wqb + 4096;
    unsigned short* Wvb = Wkb + 4096;
    unsigned short* W3b = Wvb + 4096;      // 36864 shorts
    unsigned short* W2b = W3b + 36864;     // 4096 shorts
    float* beta1 = (float*)(W2b + 4096);
    float* beta2 = beta1 + 64;

    prep_kernel<<<209, 256, 0, stream>>>(Wq, Wk, Wv, c1w, bn1s, bn1b, bn1m, bn1v,
                                         c2w, bn2s, bn2b, bn2m, bn2v,
                                         Wqb, Wkb, Wvb, W3b, W2b, beta1, beta2);
    proj_q_kernel<<<1024, 256, 0, stream>>>(x1, Wqb, bq, qb);
    proj_kv_kernel<<<1024, 256, 0, stream>>>(xc, Wkb, Wvb, bk, bv, kb, vb);
    hipFuncSetAttribute((const void*)attn_kernel,
                        hipFuncAttributeMaxDynamicSharedMemorySize, 67584);
    attn_kernel<<<512, 512, 67584, stream>>>(qb, kb, vb, xc, gam, yb);
    hipFuncSetAttribute((const void*)conv3_fused_kernel,
                        hipFuncAttributeMaxDynamicSharedMemorySize, 70720);
    conv3_fused_kernel<<<512, 512, 70720, stream>>>(yb, W3b, W2b, beta1, beta2, out);
}

// Round 13
// 215.374 us; speedup vs baseline: 1.0259x; 1.0259x over previous
//
#include <hip/hip_runtime.h>

#define HW    16384
#define CHW   1048576
#define EPSV  1e-5f
#define PITCH 68          // rows with K=64 contraction (+4 pad)
#define APITCH 132        // attention rows, K=128 contraction (+4 pad)

typedef short bf16x8 __attribute__((ext_vector_type(8)));
typedef float f32x4 __attribute__((ext_vector_type(4)));
typedef unsigned short u16x4 __attribute__((ext_vector_type(4)));
typedef unsigned short u16x8 __attribute__((ext_vector_type(8)));

static __device__ __forceinline__ unsigned short f2b(float f) {
    union { float f; unsigned int i; } x; x.f = f;
    unsigned int i = x.i + 0x7fffu + ((x.i >> 16) & 1u);   // RNE
    return (unsigned short)(i >> 16);
}

// 8 consecutive bf16 (8B-aligned LDS) as an MFMA operand fragment
static __device__ __forceinline__ bf16x8 frag_load(const unsigned short* p) {
    union { u16x4 h[2]; bf16x8 v; } u;
    u.h[0] = *(const u16x4*)(p);
    u.h[1] = *(const u16x4*)(p + 4);
    return u.v;
}
static __device__ __forceinline__ bf16x8 gfrag(const unsigned short* p) {
    return *(const bf16x8*)p;   // 16B-aligned global load (dwordx4)
}
// D[a_idx = g4+r][b_idx = i16]; both frags loaded with per-lane row = tile+i16
static __device__ __forceinline__ f32x4 mfma16(bf16x8 a, bf16x8 b, f32x4 c) {
    return __builtin_amdgcn_mfma_f32_16x16x32_bf16(a, b, c, 0, 0, 0);
}

// ---------------------------------------------------------------------------
// Kernel 0: weight prep (bf16 conversion + BN folding)
// ---------------------------------------------------------------------------
__global__ void prep_kernel(const float* __restrict__ Wq, const float* __restrict__ Wk,
                            const float* __restrict__ Wv,
                            const float* __restrict__ c1w,
                            const float* __restrict__ bn1s, const float* __restrict__ bn1b,
                            const float* __restrict__ bn1m, const float* __restrict__ bn1v,
                            const float* __restrict__ c2w,
                            const float* __restrict__ bn2s, const float* __restrict__ bn2b,
                            const float* __restrict__ bn2m, const float* __restrict__ bn2v,
                            unsigned short* __restrict__ Wqb, unsigned short* __restrict__ Wkb,
                            unsigned short* __restrict__ Wvb, unsigned short* __restrict__ W3b,
                            unsigned short* __restrict__ W2b, float* __restrict__ beta1,
                            float* __restrict__ beta2)
{
    int i = blockIdx.x * blockDim.x + threadIdx.x;
    if (i < 12288) {                                  // QKV weights: elementwise bf16
        int mat = i >> 12, r = i & 4095;
        const float* src = (mat == 0) ? Wq : ((mat == 1) ? Wk : Wv);
        unsigned short* dst = (mat == 0) ? Wqb : ((mat == 1) ? Wkb : Wvb);
        dst[r] = f2b(src[r]);
    } else if (i < 49152) {                           // conv1 3x3 folded
        int j = i - 12288;
        int dydx = j >> 12, r = j & 4095, o = r >> 6, c = r & 63;
        float inv = bn1s[o] * rsqrtf(bn1v[o] + EPSV);
        W3b[j] = f2b(c1w[o * 576 + c * 9 + dydx] * inv);
    } else if (i < 53248) {                           // conv2 1x1 folded
        int r = i - 49152, o = r >> 6;
        float inv = bn2s[o] * rsqrtf(bn2v[o] + EPSV);
        W2b[r] = f2b(c2w[r] * inv);
    } else if (i < 53376) {
        int j = i - 53248;
        if (j < 64) {
            float inv = bn1s[j] * rsqrtf(bn1v[j] + EPSV);
            beta1[j] = bn1b[j] - bn1m[j] * inv;
        } else {
            int o = j - 64;
            float inv = bn2s[o] * rsqrtf(bn2v[o] + EPSV);
            beta2[o] = bn2b[o] - bn2m[o] * inv;
        }
    }
}

// ---------------------------------------------------------------------------
// Kernel 1: fused Q/K/V projections, SEQUENTIAL staging: one 17.4 KB tile
// buffer reused for x1 then xc (half of round-7's LDS -> 8 blocks/CU thread
// cap; 32 waves/CU if VGPR<=64). xc staging loads issued BEFORE Q compute
// so HBM latency hides under Q's MFMA+stores. Single launch (no split cost).
// ---------------------------------------------------------------------------
__global__ __launch_bounds__(256, 4) void qkv_kernel(
    const float* __restrict__ x1, const float* __restrict__ xc,
    const unsigned short* __restrict__ Wqb, const unsigned short* __restrict__ Wkb,
    const unsigned short* __restrict__ Wvb,
    const float* __restrict__ bq, const float* __restrict__ bk,
    const float* __restrict__ bv,
    unsigned short* __restrict__ qo, unsigned short* __restrict__ ko,
    unsigned short* __restrict__ vo)
{
    __shared__ __align__(16) unsigned short XT[128][PITCH];   // 17408 B
    int t = threadIdx.x;
    int b = blockIdx.x >> 7;
    int p0 = (blockIdx.x & 127) << 7;
    int lane = t & 63, wid = t >> 6;
    int i16 = lane & 15;
    int g8 = (lane >> 4) << 3;
    int g4 = (lane >> 4) << 2;
    int pb = wid << 5;                 // wave's 32 positions (2 m-tiles)
    f32x4 zz = {0.f, 0.f, 0.f, 0.f};

    // ---- stage x1 tile
    const float* xs1 = x1 + b * CHW + p0;
    for (int idx = t; idx < 1024; idx += 256) {   // 32 c-pairs x 32 p-quads
        int c0 = ((idx >> 5) & 31) << 1, p4 = (idx & 31) << 2;
        float4 a0 = *(const float4*)&xs1[c0 * HW + p4];
        float4 a1 = *(const float4*)&xs1[(c0 + 1) * HW + p4];
        *(unsigned int*)&XT[p4 + 0][c0] = f2b(a0.x) | ((unsigned int)f2b(a1.x) << 16);
        *(unsigned int*)&XT[p4 + 1][c0] = f2b(a0.y) | ((unsigned int)f2b(a1.y) << 16);
        *(unsigned int*)&XT[p4 + 2][c0] = f2b(a0.z) | ((unsigned int)f2b(a1.z) << 16);
        *(unsigned int*)&XT[p4 + 3][c0] = f2b(a0.w) | ((unsigned int)f2b(a1.w) << 16);
    }
    __syncthreads();

    bf16x8 afr[2][2];                  // [mi][ks]
    #pragma unroll
    for (int mi = 0; mi < 2; ++mi)
        #pragma unroll
        for (int ks = 0; ks < 2; ++ks)
            afr[mi][ks] = frag_load(&XT[pb + mi * 16 + i16][ks * 32 + g8]);
    __syncthreads();   // all waves hold x1 frags; XT free for reuse

    // ---- issue xc staging (loads fly while Q computes below)
    const float* xs2 = xc + b * CHW + p0;
    for (int idx = t; idx < 1024; idx += 256) {
        int c0 = ((idx >> 5) & 31) << 1, p4 = (idx & 31) << 2;
        float4 a0 = *(const float4*)&xs2[c0 * HW + p4];
        float4 a1 = *(const float4*)&xs2[(c0 + 1) * HW + p4];
        *(unsigned int*)&XT[p4 + 0][c0] = f2b(a0.x) | ((unsigned int)f2b(a1.x) << 16);
        *(unsigned int*)&XT[p4 + 1][c0] = f2b(a0.y) | ((unsigned int)f2b(a1.y) << 16);
        *(unsigned int*)&XT[p4 + 2][c0] = f2b(a0.z) | ((unsigned int)f2b(a1.z) << 16);
        *(unsigned int*)&XT[p4 + 3][c0] = f2b(a0.w) | ((unsigned int)f2b(a1.w) << 16);
    }

    // ---- Q = x1 . Wq^T (overlaps the xc loads above)
    {
        f32x4 acc[2][4];
        #pragma unroll
        for (int mi = 0; mi < 2; ++mi)
            #pragma unroll
            for (int nt = 0; nt < 4; ++nt) acc[mi][nt] = zz;
        #pragma unroll
        for (int ks = 0; ks < 2; ++ks)
            #pragma unroll
            for (int nt = 0; nt < 4; ++nt) {
                bf16x8 bw = gfrag(Wqb + (nt * 16 + i16) * 64 + ks * 32 + g8);
                acc[0][nt] = mfma16(afr[0][ks], bw, acc[0][nt]);
                acc[1][nt] = mfma16(afr[1][ks], bw, acc[1][nt]);
            }
        unsigned short* dst = qo + b * CHW + p0;
        #pragma unroll
        for (int nt = 0; nt < 4; ++nt) {
            int o = nt * 16 + i16;
            float bb = bq[o];
            #pragma unroll
            for (int mi = 0; mi < 2; ++mi) {
                u16x4 pk;
                pk[0] = f2b(acc[mi][nt][0] + bb);
                pk[1] = f2b(acc[mi][nt][1] + bb);
                pk[2] = f2b(acc[mi][nt][2] + bb);
                pk[3] = f2b(acc[mi][nt][3] + bb);
                *(u16x4*)&dst[o * HW + pb + mi * 16 + g4] = pk;
            }
        }
    }
    __syncthreads();   // xc tile fully staged

    #pragma unroll
    for (int mi = 0; mi < 2; ++mi)
        #pragma unroll
        for (int ks = 0; ks < 2; ++ks)
            afr[mi][ks] = frag_load(&XT[pb + mi * 16 + i16][ks * 32 + g8]);

    // ---- K, V = xc . W^T (sequential mats, shared frags)
    #pragma unroll
    for (int mat = 0; mat < 2; ++mat) {
        const unsigned short* Wmat = (mat == 0) ? Wkb : Wvb;
        unsigned short* dst = ((mat == 0) ? ko : vo) + b * CHW + p0;
        const float* bias = (mat == 0) ? bk : bv;

        f32x4 acc[2][4];
        #pragma unroll
        for (int mi = 0; mi < 2; ++mi)
            #pragma unroll
            for (int nt = 0; nt < 4; ++nt) acc[mi][nt] = zz;

        #pragma unroll
        for (int ks = 0; ks < 2; ++ks)
            #pragma unroll
            for (int nt = 0; nt < 4; ++nt) {
                bf16x8 bw = gfrag(Wmat + (nt * 16 + i16) * 64 + ks * 32 + g8);
                acc[0][nt] = mfma16(afr[0][ks], bw, acc[0][nt]);
                acc[1][nt] = mfma16(afr[1][ks], bw, acc[1][nt]);
            }

        #pragma unroll
        for (int nt = 0; nt < 4; ++nt) {
            int o = nt * 16 + i16;
            float bb = bias[o];
            #pragma unroll
            for (int mi = 0; mi < 2; ++mi) {
                u16x4 pk;
                pk[0] = f2b(acc[mi][nt][0] + bb);
                pk[1] = f2b(acc[mi][nt][1] + bb);
                pk[2] = f2b(acc[mi][nt][2] + bb);
                pk[3] = f2b(acc[mi][nt][3] + bb);
                *(u16x4*)&dst[o * HW + pb + mi * 16 + g4] = pk;
            }
        }
    }
}

// ---------------------------------------------------------------------------
// Kernel 2: attention per (b,c), 512 threads / 8 waves, wave owns 16 v-rows.
// QK^T: A=KT, B=QT (softmax reduction stays in-wave). PV swapped: A=PL (v),
// B=V direct-from-global (h) -> y stores packed u16x4, xc reads float4.
// Dynamic LDS: QT,KT [128][132] bf16 = 67584 B. VGPR ~128 -> 16 waves/CU cap.
// ---------------------------------------------------------------------------
__global__ __launch_bounds__(512) void attn_kernel(
    const unsigned short* __restrict__ q, const unsigned short* __restrict__ k,
    const unsigned short* __restrict__ v, const float* __restrict__ xc,
    const float* __restrict__ gamma_p, unsigned short* __restrict__ y)
{
    extern __shared__ __align__(16) unsigned short sarena[];
    unsigned short (*QT)[APITCH] = (unsigned short(*)[APITCH])sarena;
    unsigned short (*KT)[APITCH] = (unsigned short(*)[APITCH])(sarena + 16896);
    unsigned short (*PL)[APITCH] = QT;      // aliases QT after phase 1

    int t = threadIdx.x;
    int base = blockIdx.x * HW;

    for (int idx = t; idx < 1024; idx += 512) {    // 64 h-pairs x 16 w-octets
        int h0 = (idx >> 4) << 1, w8 = (idx & 15) << 3;
        u16x8 q0 = *(const u16x8*)&q[base + h0 * 128 + w8];
        u16x8 q1 = *(const u16x8*)&q[base + (h0 + 1) * 128 + w8];
        #pragma unroll
        for (int j = 0; j < 8; ++j)
            *(unsigned int*)&QT[w8 + j][h0] = (unsigned int)q0[j] | ((unsigned int)q1[j] << 16);
        u16x8 k0 = *(const u16x8*)&k[base + h0 * 128 + w8];
        u16x8 k1 = *(const u16x8*)&k[base + (h0 + 1) * 128 + w8];
        #pragma unroll
        for (int j = 0; j < 8; ++j)
            *(unsigned int*)&KT[w8 + j][h0] = (unsigned int)k0[j] | ((unsigned int)k1[j] << 16);
    }
    __syncthreads();

    int lane = t & 63, wid = t >> 6;
    int i16 = lane & 15;
    int g8 = (lane >> 4) << 3;
    int g4 = (lane >> 4) << 2;
    int m0 = wid << 4;               // 16 v-rows per wave

    f32x4 zz = {0.f, 0.f, 0.f, 0.f};
    f32x4 e[8];
    #pragma unroll
    for (int nt = 0; nt < 8; ++nt) e[nt] = zz;

    #pragma unroll
    for (int ks = 0; ks < 4; ++ks) {
        bf16x8 a0 = frag_load(&KT[m0 + i16][ks * 32 + g8]);
        #pragma unroll
        for (int nt = 0; nt < 8; ++nt) {
            bf16x8 bfq = frag_load(&QT[nt * 16 + i16][ks * 32 + g8]);
            e[nt] = mfma16(a0, bfq, e[nt]);
        }
    }
    __syncthreads();   // QT/KT reads complete; QT region becomes PL

    // softmax over w: reduce across nt (regs) and the 16-lane col group
    #pragma unroll
    for (int r = 0; r < 4; ++r) {
        float mx = e[0][r];
        #pragma unroll
        for (int nt = 1; nt < 8; ++nt) mx = fmaxf(mx, e[nt][r]);
        mx = fmaxf(mx, __shfl_xor(mx, 1));
        mx = fmaxf(mx, __shfl_xor(mx, 2));
        mx = fmaxf(mx, __shfl_xor(mx, 4));
        mx = fmaxf(mx, __shfl_xor(mx, 8));
        float pv[8];
        float s = 0.f;
        #pragma unroll
        for (int nt = 0; nt < 8; ++nt) {
            pv[nt] = __expf(e[nt][r] - mx);
            s += pv[nt];
        }
        s += __shfl_xor(s, 1);
        s += __shfl_xor(s, 2);
        s += __shfl_xor(s, 4);
        s += __shfl_xor(s, 8);
        float rinv = 1.f / s;
        int vr = m0 + g4 + r;
        #pragma unroll
        for (int nt = 0; nt < 8; ++nt)
            PL[vr][nt * 16 + i16] = f2b(pv[nt] * rinv);
    }
    // no barrier: PV's A-frags read only this wave's own 16 PL rows

    f32x4 o_[8];
    #pragma unroll
    for (int nt = 0; nt < 8; ++nt) o_[nt] = zz;

    bf16x8 ap[4];
    #pragma unroll
    for (int ks = 0; ks < 4; ++ks)
        ap[ks] = frag_load(&PL[m0 + i16][ks * 32 + g8]);

    const unsigned short* vb_ = v + base;
    #pragma unroll
    for (int ks = 0; ks < 4; ++ks)
        #pragma unroll
        for (int nt = 0; nt < 8; ++nt) {
            bf16x8 bv8 = gfrag(vb_ + (nt * 16 + i16) * 128 + ks * 32 + g8);
            o_[nt] = mfma16(ap[ks], bv8, o_[nt]);
        }

    float g = gamma_p[0];
    const float* xcb = xc + base;
    #pragma unroll
    for (int nt = 0; nt < 8; ++nt) {
        int hh = nt * 16 + i16;
        int v4 = m0 + g4;
        float4 xcv = *(const float4*)&xcb[hh * 128 + v4];
        u16x4 pk;
        pk[0] = f2b(fmaf(g, o_[nt][0], xcv.x));
        pk[1] = f2b(fmaf(g, o_[nt][1], xcv.y));
        pk[2] = f2b(fmaf(g, o_[nt][2], xcv.z));
        pk[3] = f2b(fmaf(g, o_[nt][3], xcv.w));
        *(u16x4*)&y[base + hh * 128 + v4] = pk;
    }
}

// ---------------------------------------------------------------------------
// Kernel 3: 3x3 conv + BN + ReLU + 1x1 conv + BN + ReLU, fused, MFMA.
// conv1: A=W3 (o), B=XT (p) -> packed Y2 u16x4 writes.
// conv2 swapped: A=Y2 (p), B=W2 (o2) -> packed float4 output stores.
// Dynamic LDS 70720 B: XT [4][130][68] (Y2 [256][68] aliases) -> 2 blocks/CU.
// ---------------------------------------------------------------------------
__global__ __launch_bounds__(512) void conv3_fused_kernel(
    const unsigned short* __restrict__ yin, const unsigned short* __restrict__ W3b,
    const unsigned short* __restrict__ W2b, const float* __restrict__ beta1,
    const float* __restrict__ beta2, float* __restrict__ out)
{
    extern __shared__ __align__(16) unsigned short arena[];
    unsigned short* XT = arena;              // 4*130*68 = 35360 shorts
    unsigned short* Y2 = arena;              // [256][68] alias (XT dead by then)

    int t = threadIdx.x;
    int b = blockIdx.x >> 6;
    int h0 = (blockIdx.x & 63) << 1;

    u16x4 z4 = {0, 0, 0, 0};
    if (t < 136) {                                    // zero w-halo rows 0,129
        int dy = t / 34, rr = t % 34;
        int row = (rr < 17) ? 0 : 129;
        int q4 = (rr % 17) << 2;
        *(u16x4*)&XT[(dy * 130 + row) * PITCH + q4] = z4;
    }
    const unsigned short* yb = yin + b * CHW;
    for (int idx = t; idx < 2048; idx += 512) {  // 4 dy x 32 c-pairs x 16 w-octets
        int dy = idx >> 9, c0 = ((idx >> 4) & 31) << 1, w8 = (idx & 15) << 3;
        int hh = h0 + dy - 1;
        u16x8 a0 = {0,0,0,0,0,0,0,0}, a1 = {0,0,0,0,0,0,0,0};
        if (hh >= 0 && hh < 128) {
            a0 = *(const u16x8*)&yb[c0 * HW + hh * 128 + w8];
            a1 = *(const u16x8*)&yb[(c0 + 1) * HW + hh * 128 + w8];
        }
        #pragma unroll
        for (int j = 0; j < 8; ++j)
            *(unsigned int*)&XT[(dy * 130 + w8 + 1 + j) * PITCH + c0] =
                (unsigned int)a0[j] | ((unsigned int)a1[j] << 16);
    }
    __syncthreads();

    int lane = t & 63, wid = t >> 6;
    int i16 = lane & 15;
    int g8 = (lane >> 4) << 3;
    int g4 = (lane >> 4) << 2;
    int orow  = wid >> 2;              // output row within pair
    int wbase = ((wid >> 1) & 1) << 6; // 64-wide half of the row
    int mbase = (wid & 1) << 1;        // 2 of the 4 o-tiles

    f32x4 zz = {0.f, 0.f, 0.f, 0.f};
    f32x4 acc[2][4];
    #pragma unroll
    for (int m = 0; m < 2; ++m)
        #pragma unroll
        for (int nt = 0; nt < 4; ++nt) acc[m][nt] = zz;

    #pragma unroll
    for (int dy = 0; dy < 3; ++dy)
        #pragma unroll
        for (int dx = 0; dx < 3; ++dx) {
            const unsigned short* wpl = W3b + (dy * 3 + dx) * 4096;
            const unsigned short* xpl = XT + ((dy + orow) * 130 + dx) * PITCH;
            #pragma unroll
            for (int ks = 0; ks < 2; ++ks) {
                bf16x8 bf0 = frag_load(xpl + (wbase + i16) * PITCH + ks * 32 + g8);
                bf16x8 bf1 = frag_load(xpl + (wbase + 16 + i16) * PITCH + ks * 32 + g8);
                bf16x8 bf2 = frag_load(xpl + (wbase + 32 + i16) * PITCH + ks * 32 + g8);
                bf16x8 bf3 = frag_load(xpl + (wbase + 48 + i16) * PITCH + ks * 32 + g8);
                #pragma unroll
                for (int m = 0; m < 2; ++m) {
                    bf16x8 a = gfrag(wpl + ((mbase + m) * 16 + i16) * 64 + ks * 32 + g8);
                    acc[m][0] = mfma16(a, bf0, acc[m][0]);
                    acc[m][1] = mfma16(a, bf1, acc[m][1]);
                    acc[m][2] = mfma16(a, bf2, acc[m][2]);
                    acc[m][3] = mfma16(a, bf3, acc[m][3]);
                }
            }
        }
    __syncthreads();   // all XT reads done before aliasing as Y2

    #pragma unroll
    for (int m = 0; m < 2; ++m) {
        int ob0 = (mbase + m) * 16 + g4;
        float b0 = beta1[ob0 + 0];
        float b1 = beta1[ob0 + 1];
        float b2 = beta1[ob0 + 2];
        float b3 = beta1[ob0 + 3];
        #pragma unroll
        for (int nt = 0; nt < 4; ++nt) {
            int p = orow * 128 + wbase + nt * 16 + i16;
            u16x4 pk;
            pk[0] = f2b(fmaxf(acc[m][nt][0] + b0, 0.f));
            pk[1] = f2b(fmaxf(acc[m][nt][1] + b1, 0.f));
            pk[2] = f2b(fmaxf(acc[m][nt][2] + b2, 0.f));
            pk[3] = f2b(fmaxf(acc[m][nt][3] + b3, 0.f));
            *(u16x4*)&Y2[p * PITCH + ob0] = pk;
        }
    }
    __syncthreads();

    // conv2 swapped: A = Y2 (p rows), B = W2 (o2 rows)
    int m0c = wid << 5;                // wave's 32 positions
    f32x4 acc2[2][4];
    #pragma unroll
    for (int m = 0; m < 2; ++m)
        #pragma unroll
        for (int nt = 0; nt < 4; ++nt) acc2[m][nt] = zz;

    #pragma unroll
    for (int ks = 0; ks < 2; ++ks) {
        bf16x8 ay0 = frag_load(Y2 + (m0c + i16) * PITCH + ks * 32 + g8);
        bf16x8 ay1 = frag_load(Y2 + (m0c + 16 + i16) * PITCH + ks * 32 + g8);
        #pragma unroll
        for (int nt = 0; nt < 4; ++nt) {
            bf16x8 bw = gfrag(W2b + (nt * 16 + i16) * 64 + ks * 32 + g8);
            acc2[0][nt] = mfma16(ay0, bw, acc2[0][nt]);
            acc2[1][nt] = mfma16(ay1, bw, acc2[1][nt]);
        }
    }

    float* ob = out + b * CHW;
    #pragma unroll
    for (int mi = 0; mi < 2; ++mi)
        #pragma unroll
        for (int nt = 0; nt < 4; ++nt) {
            int o2 = nt * 16 + i16;
            float bt = beta2[o2];
            int p = m0c + mi * 16 + g4;
            int orw = p >> 7, wl = p & 127;
            float4 vv;
            vv.x = fmaxf(acc2[mi][nt][0] + bt, 0.f);
            vv.y = fmaxf(acc2[mi][nt][1] + bt, 0.f);
            vv.z = fmaxf(acc2[mi][nt][2] + bt, 0.f);
            vv.w = fmaxf(acc2[mi][nt][3] + bt, 0.f);
            *(float4*)&ob[o2 * HW + (h0 + orw) * 128 + wl] = vv;
        }
}

// ---------------------------------------------------------------------------
extern "C" void kernel_launch(void* const* d_in, const int* in_sizes, int n_in,
                              void* d_out, int out_size, void* d_ws, size_t ws_size,
                              hipStream_t stream)
{
    const float* x1   = (const float*)d_in[0];
    const float* xc   = (const float*)d_in[1];
    const float* Wq   = (const float*)d_in[2];
    const float* bq   = (const float*)d_in[3];
    const float* Wk   = (const float*)d_in[4];
    const float* bk   = (const float*)d_in[5];
    const float* Wv   = (const float*)d_in[6];
    const float* bv   = (const float*)d_in[7];
    const float* gam  = (const float*)d_in[8];
    const float* c1w  = (const float*)d_in[9];
    const float* bn1s = (const float*)d_in[10];
    const float* bn1b = (const float*)d_in[11];
    const float* bn1m = (const float*)d_in[12];
    const float* bn1v = (const float*)d_in[13];
    const float* c2w  = (const float*)d_in[14];
    const float* bn2s = (const float*)d_in[15];
    const float* bn2b = (const float*)d_in[16];
    const float* bn2m = (const float*)d_in[17];
    const float* bn2v = (const float*)d_in[18];
    float* out = (float*)d_out;

    char* ws = (char*)d_ws;
    const size_t BUF = 16777216;   // one bf16 [B,C,H,W] buffer
    unsigned short* qb  = (unsigned short*)(ws);
    unsigned short* kb  = (unsigned short*)(ws + BUF);
    unsigned short* vb  = (unsigned short*)(ws + 2 * BUF);
    unsigned short* yb  = (unsigned short*)(ws + 3 * BUF);
    unsigned short* Wqb = (unsigned short*)(ws + 4 * BUF);
    unsigned short* Wkb = Wqb + 4096;
    unsigned short* Wvb = Wkb + 4096;
    unsigned short* W3b = Wvb + 4096;      // 36864 shorts
    unsigned short* W2b = W3b + 36864;     // 4096 shorts
    float* beta1 = (float*)(W2b + 4096);
    float* beta2 = beta1 + 64;

    prep_kernel<<<209, 256, 0, stream>>>(Wq, Wk, Wv, c1w, bn1s, bn1b, bn1m, bn1v,
                                         c2w, bn2s, bn2b, bn2m, bn2v,
                                         Wqb, Wkb, Wvb, W3b, W2b, beta1, beta2);
    qkv_kernel<<<1024, 256, 0, stream>>>(x1, xc, Wqb, Wkb, Wvb, bq, bk, bv,
                                         qb, kb, vb);
    hipFuncSetAttribute((const void*)attn_kernel,
                        hipFuncAttributeMaxDynamicSharedMemorySize, 67584);
    attn_kernel<<<512, 512, 67584, stream>>>(qb, kb, vb, xc, gam, yb);
    hipFuncSetAttribute((const void*)conv3_fused_kernel,
                        hipFuncAttributeMaxDynamicSharedMemorySize, 70720);
    conv3_fused_kernel<<<512, 512, 70720, stream>>>(yb, W3b, W2b, beta1, beta2, out);
}